// Round 10
// baseline (361.833 us; speedup 1.0000x reference)
//
#include <hip/hip_runtime.h>
#include <math.h>

// QSAR fused pipeline, one 256-thread block per molecule. B=4096, A=64, D=6, AF=37, BF=6, H=128.
// R10: reduce redundant L2 weight traffic (the measured ~240us wall):
//  - P5: wave-per-8-perm-atoms, 2 rounds, float2 Wo loads -> ~4 passes over Wo per block
//    (was 8+), all waves streaming in the same order (L1 hits). No internal barriers.
//  - conv1/conv2: work atoms counting-sorted by degree; one wave per degree bucket
//    (8 atoms/chunk, 16 named accumulators) -> W[d] streamed ~once per block, not per atom.
// Envelope: (256,4) / VGPR cap 128 (R4-proven, 52 VGPR). Spill tripwire: WRITE_SIZE ~128KB.
// Spill discipline: named regs, unconditional accumulators, conditional writes only.

#define ACC16_FMA(W2V) \
  a0x = fmaf(f0, (W2V).x, a0x); a0y = fmaf(f0, (W2V).y, a0y); \
  a1x = fmaf(f1, (W2V).x, a1x); a1y = fmaf(f1, (W2V).y, a1y); \
  a2x = fmaf(f2, (W2V).x, a2x); a2y = fmaf(f2, (W2V).y, a2y); \
  a3x = fmaf(f3, (W2V).x, a3x); a3y = fmaf(f3, (W2V).y, a3y); \
  a4x = fmaf(f4, (W2V).x, a4x); a4y = fmaf(f4, (W2V).y, a4y); \
  a5x = fmaf(f5, (W2V).x, a5x); a5y = fmaf(f5, (W2V).y, a5y); \
  a6x = fmaf(f6, (W2V).x, a6x); a6y = fmaf(f6, (W2V).y, a6y); \
  a7x = fmaf(f7, (W2V).x, a7x); a7y = fmaf(f7, (W2V).y, a7y);

__device__ __forceinline__ float4 max4(float4 a, float4 b) {
  return make_float4(fmaxf(a.x, b.x), fmaxf(a.y, b.y), fmaxf(a.z, b.z), fmaxf(a.w, b.w));
}

__device__ __forceinline__ float4 nbr_max(const float4* sx4, const int* se, int a, int c4) {
  float4 m = sx4[a * 32 + c4];
#pragma unroll
  for (int d = 0; d < 6; ++d) {
    int e = se[a * 6 + d];
    if (e >= 0) m = max4(m, sx4[e * 32 + c4]);
  }
  return m;
}

__device__ __forceinline__ float4 nbr_sum(const float4* sx4, const int* se, int a, int c4) {
  float4 s = sx4[a * 32 + c4];
#pragma unroll
  for (int d = 0; d < 6; ++d) {
    int e = se[a * 6 + d];
    if (e >= 0) {
      float4 v = sx4[e * 32 + c4];
      s.x += v.x; s.y += v.y; s.z += v.z; s.w += v.w;
    }
  }
  return s;
}

// pool2: max over WORK members only; non-work x2 rows are implicitly 0, relu>=0 -> 0-init exact.
__device__ __forceinline__ float4 nbr_wmax(const float4* sx4, const int* se, const int* sdeg,
                                           int a, int c4) {
  float4 m = make_float4(0.f, 0.f, 0.f, 0.f);
  if (sdeg[a] < 6) m = max4(m, sx4[a * 32 + c4]);
#pragma unroll
  for (int d = 0; d < 6; ++d) {
    int e = se[a * 6 + d];
    if (e >= 0 && sdeg[e] < 6) m = max4(m, sx4[e * 32 + c4]);
  }
  return m;
}

__global__ __launch_bounds__(256, 4) void qsar_fused(
    const float* __restrict__ atoms, const float* __restrict__ bonds,
    const int* __restrict__ edges,
    const float* __restrict__ W1, const float* __restrict__ b1,
    const float* __restrict__ W2, const float* __restrict__ b2,
    const float* __restrict__ Wo, const float* __restrict__ bo,
    const float* __restrict__ Wm1, const float* __restrict__ bm1,
    const float* __restrict__ Wm2, const float* __restrict__ bm2,
    const float* __restrict__ Wm3, const float* __restrict__ bm3,
    float* __restrict__ out)
{
  const int b   = blockIdx.x;
  const int tid = threadIdx.x;        // 0..255
  const int wv  = tid >> 6;           // wave 0..3
  const int ln  = tid & 63;           // lane in wave

  __shared__ float s_x[64 * 128];     // 32768 B
  __shared__ float s_sa[64 * 38];     // 9728 B: summed-atom feats by work index; fp/h1/h2 alias
  __shared__ float s_bsum[64 * 8];    // 2048 B
  __shared__ int   s_edges[64 * 6];   // 1536 B
  __shared__ int   s_deg[64];
  __shared__ int   s_work[64];        // work atoms, sorted by degree (counting sort)
  __shared__ int   s_perm[64];        // nonzero-x2p atoms [0,na), zero atoms [na,64)
  __shared__ float s_rsum[64];
  __shared__ int   s_dcnt[6], s_dfill[6], s_doff[7];
  __shared__ int   s_nwork, s_na, s_nz;

  float4* sx4  = reinterpret_cast<float4*>(s_x);
  float*  s_fp = s_sa;                // 256 floats (s_sa dead after conv1)
  float*  s_h1 = s_sa + 256;          // 64
  float*  s_h2 = s_sa + 320;          // 32

  // ---------------- P0: stage edges, bsum; zero s_x; init counters --------------------
  {
    const int* ge = edges + (size_t)b * (64 * 6);
    for (int i = tid; i < 64 * 6; i += 256) s_edges[i] = ge[i];
    const float* gb = bonds + (size_t)b * (64 * 36);
    for (int i = tid; i < 64 * 6; i += 256) {
      int a = i / 6, f = i - a * 6;
      float s = 0.f;
#pragma unroll
      for (int d = 0; d < 6; ++d) s += gb[a * 36 + d * 6 + f];
      s_bsum[a * 8 + f] = s;
    }
#pragma unroll
    for (int j = 0; j < 8; ++j) sx4[tid + j * 256] = make_float4(0.f, 0.f, 0.f, 0.f);
    if (tid < 6) s_dcnt[tid] = 0;
    if (tid == 0) { s_na = 0; s_nz = 0; }
  }
  __syncthreads();

  // ---------------- P0b: degree + per-degree counts -----------------------------------
  if (tid < 64) {
    int dcnt = 0;
#pragma unroll
    for (int d = 0; d < 6; ++d) dcnt += (s_edges[tid * 6 + d] >= 0) ? 1 : 0;
    s_deg[tid] = dcnt;
    if (dcnt < 6) atomicAdd(&s_dcnt[dcnt], 1);
  }
  __syncthreads();

  // ---------------- P0c: bucket offsets (tid 0) + perm classification (tid<64) --------
  if (tid == 0) {
    int off = 0;
#pragma unroll
    for (int d = 0; d < 6; ++d) { s_doff[d] = off; s_dfill[d] = off; off += s_dcnt[d]; }
    s_doff[6] = off;
    s_nwork = off;
  }
  if (tid < 64) {
    int nzf = (s_deg[tid] < 6) ? 1 : 0;
#pragma unroll
    for (int d = 0; d < 6; ++d) {
      int e = s_edges[tid * 6 + d];
      if (e >= 0 && s_deg[e] < 6) nzf = 1;
    }
    if (nzf) { int p = atomicAdd(&s_na, 1); s_perm[p] = tid; }
    else     { int p = atomicAdd(&s_nz, 1); s_perm[63 - p] = tid; }
  }
  __syncthreads();

  // ---------------- P0d: fill degree-sorted worklist -----------------------------------
  if (tid < 64 && s_deg[tid] < 6) {
    int p = atomicAdd(&s_dfill[s_deg[tid]], 1);
    s_work[p] = tid;
  }
  __syncthreads();

  // ---------------- P1a: gather summed feats for ALL work atoms into s_sa --------------
  {
    const int nw = s_nwork;
    const float* ga = atoms + (size_t)b * (64 * 37);
    for (int i = tid; i < nw * 37; i += 256) {
      int wi = i / 37, k = i - wi * 37;
      int a = s_work[wi];
      float f = ga[a * 37 + k];
#pragma unroll
      for (int d = 0; d < 6; ++d) {
        int e = s_edges[a * 6 + d];
        if (e >= 0) f += ga[e * 37 + k];
      }
      s_sa[wi * 38 + k] = f;
    }
  }
  __syncthreads();

  // ---------------- P1b: conv1, one wave per degree bucket, 8 atoms/chunk --------------
  // Wave wv handles d=wv and d=wv+4 (<=5). Feature rows 0..36 from s_sa; weight rows
  // 37..42 are the bsum rows (R5 lesson: NEVER run them against s_sa). s_x pre-zeroed;
  // conv1 writes only its own bucket's rows; no s_x readers here.
  {
    for (int pass = 0; pass < 2; ++pass) {
      const int d = wv + pass * 4;
      if (d <= 5) {
        const int beg = s_doff[d], e = s_doff[d + 1];
        if (beg < e) {
          const float2* wp2 = reinterpret_cast<const float2*>(W1 + (size_t)d * (43 * 128));
          const float2 bb = reinterpret_cast<const float2*>(b1 + (size_t)d * 128)[ln];
          for (int j = beg; j < e; j += 8) {
            const int c1 = (j + 1 < e) ? j + 1 : j, c2 = (j + 2 < e) ? j + 2 : j;
            const int c3 = (j + 3 < e) ? j + 3 : j, c4 = (j + 4 < e) ? j + 4 : j;
            const int c5 = (j + 5 < e) ? j + 5 : j, c6 = (j + 6 < e) ? j + 6 : j;
            const int c7 = (j + 7 < e) ? j + 7 : j;
            const int at0 = s_work[j],  at1 = s_work[c1], at2 = s_work[c2], at3 = s_work[c3];
            const int at4 = s_work[c4], at5 = s_work[c5], at6 = s_work[c6], at7 = s_work[c7];
            float a0x = bb.x, a0y = bb.y, a1x = bb.x, a1y = bb.y;
            float a2x = bb.x, a2y = bb.y, a3x = bb.x, a3y = bb.y;
            float a4x = bb.x, a4y = bb.y, a5x = bb.x, a5y = bb.y;
            float a6x = bb.x, a6y = bb.y, a7x = bb.x, a7y = bb.y;
            float f0, f1, f2, f3, f4, f5, f6, f7;
#pragma unroll 2
            for (int k = 0; k < 37; ++k) {
              const float2 w = wp2[k * 64 + ln];
              f0 = s_sa[j  * 38 + k]; f1 = s_sa[c1 * 38 + k];
              f2 = s_sa[c2 * 38 + k]; f3 = s_sa[c3 * 38 + k];
              f4 = s_sa[c4 * 38 + k]; f5 = s_sa[c5 * 38 + k];
              f6 = s_sa[c6 * 38 + k]; f7 = s_sa[c7 * 38 + k];
              ACC16_FMA(w)
            }
#pragma unroll
            for (int kk = 0; kk < 6; ++kk) {
              const float2 w = wp2[(37 + kk) * 64 + ln];
              f0 = s_bsum[at0 * 8 + kk]; f1 = s_bsum[at1 * 8 + kk];
              f2 = s_bsum[at2 * 8 + kk]; f3 = s_bsum[at3 * 8 + kk];
              f4 = s_bsum[at4 * 8 + kk]; f5 = s_bsum[at5 * 8 + kk];
              f6 = s_bsum[at6 * 8 + kk]; f7 = s_bsum[at7 * 8 + kk];
              ACC16_FMA(w)
            }
            *reinterpret_cast<float2*>(&s_x[at0 * 128 + 2 * ln]) =
                make_float2(fmaxf(a0x, 0.f), fmaxf(a0y, 0.f));
            if (j + 1 < e) *reinterpret_cast<float2*>(&s_x[at1 * 128 + 2 * ln]) =
                make_float2(fmaxf(a1x, 0.f), fmaxf(a1y, 0.f));
            if (j + 2 < e) *reinterpret_cast<float2*>(&s_x[at2 * 128 + 2 * ln]) =
                make_float2(fmaxf(a2x, 0.f), fmaxf(a2y, 0.f));
            if (j + 3 < e) *reinterpret_cast<float2*>(&s_x[at3 * 128 + 2 * ln]) =
                make_float2(fmaxf(a3x, 0.f), fmaxf(a3y, 0.f));
            if (j + 4 < e) *reinterpret_cast<float2*>(&s_x[at4 * 128 + 2 * ln]) =
                make_float2(fmaxf(a4x, 0.f), fmaxf(a4y, 0.f));
            if (j + 5 < e) *reinterpret_cast<float2*>(&s_x[at5 * 128 + 2 * ln]) =
                make_float2(fmaxf(a5x, 0.f), fmaxf(a5y, 0.f));
            if (j + 6 < e) *reinterpret_cast<float2*>(&s_x[at6 * 128 + 2 * ln]) =
                make_float2(fmaxf(a6x, 0.f), fmaxf(a6y, 0.f));
            if (j + 7 < e) *reinterpret_cast<float2*>(&s_x[at7 * 128 + 2 * ln]) =
                make_float2(fmaxf(a7x, 0.f), fmaxf(a7y, 0.f));
          }
        }
      }
    }
  }
  __syncthreads();

  // ---------------- P2: pool1 in place (all rows), float4 ------------------------------
  {
    float4 v0 = nbr_max(sx4, s_edges, (tid + 0 * 256) >> 5, tid & 31);
    float4 v1 = nbr_max(sx4, s_edges, (tid + 1 * 256) >> 5, tid & 31);
    float4 v2 = nbr_max(sx4, s_edges, (tid + 2 * 256) >> 5, tid & 31);
    float4 v3 = nbr_max(sx4, s_edges, (tid + 3 * 256) >> 5, tid & 31);
    float4 v4 = nbr_max(sx4, s_edges, (tid + 4 * 256) >> 5, tid & 31);
    float4 v5 = nbr_max(sx4, s_edges, (tid + 5 * 256) >> 5, tid & 31);
    float4 v6 = nbr_max(sx4, s_edges, (tid + 6 * 256) >> 5, tid & 31);
    float4 v7 = nbr_max(sx4, s_edges, (tid + 7 * 256) >> 5, tid & 31);
    __syncthreads();
    sx4[tid + 0 * 256] = v0; sx4[tid + 1 * 256] = v1;
    sx4[tid + 2 * 256] = v2; sx4[tid + 3 * 256] = v3;
    sx4[tid + 4 * 256] = v4; sx4[tid + 5 * 256] = v5;
    sx4[tid + 6 * 256] = v6; sx4[tid + 7 * 256] = v7;
  }
  __syncthreads();

  // ---------------- P2b: ysum for work rows in place -----------------------------------
  {
    const float4 z = make_float4(0.f, 0.f, 0.f, 0.f);
    float4 v0 = z, v1 = z, v2 = z, v3 = z, v4 = z, v5 = z, v6 = z, v7 = z;
    if (s_deg[(tid + 0 * 256) >> 5] < 6) v0 = nbr_sum(sx4, s_edges, (tid + 0 * 256) >> 5, tid & 31);
    if (s_deg[(tid + 1 * 256) >> 5] < 6) v1 = nbr_sum(sx4, s_edges, (tid + 1 * 256) >> 5, tid & 31);
    if (s_deg[(tid + 2 * 256) >> 5] < 6) v2 = nbr_sum(sx4, s_edges, (tid + 2 * 256) >> 5, tid & 31);
    if (s_deg[(tid + 3 * 256) >> 5] < 6) v3 = nbr_sum(sx4, s_edges, (tid + 3 * 256) >> 5, tid & 31);
    if (s_deg[(tid + 4 * 256) >> 5] < 6) v4 = nbr_sum(sx4, s_edges, (tid + 4 * 256) >> 5, tid & 31);
    if (s_deg[(tid + 5 * 256) >> 5] < 6) v5 = nbr_sum(sx4, s_edges, (tid + 5 * 256) >> 5, tid & 31);
    if (s_deg[(tid + 6 * 256) >> 5] < 6) v6 = nbr_sum(sx4, s_edges, (tid + 6 * 256) >> 5, tid & 31);
    if (s_deg[(tid + 7 * 256) >> 5] < 6) v7 = nbr_sum(sx4, s_edges, (tid + 7 * 256) >> 5, tid & 31);
    __syncthreads();
    if (s_deg[(tid + 0 * 256) >> 5] < 6) sx4[tid + 0 * 256] = v0;
    if (s_deg[(tid + 1 * 256) >> 5] < 6) sx4[tid + 1 * 256] = v1;
    if (s_deg[(tid + 2 * 256) >> 5] < 6) sx4[tid + 2 * 256] = v2;
    if (s_deg[(tid + 3 * 256) >> 5] < 6) sx4[tid + 3 * 256] = v3;
    if (s_deg[(tid + 4 * 256) >> 5] < 6) sx4[tid + 4 * 256] = v4;
    if (s_deg[(tid + 5 * 256) >> 5] < 6) sx4[tid + 5 * 256] = v5;
    if (s_deg[(tid + 6 * 256) >> 5] < 6) sx4[tid + 6 * 256] = v6;
    if (s_deg[(tid + 7 * 256) >> 5] < 6) sx4[tid + 7 * 256] = v7;
  }
  __syncthreads();

  // ---------------- P3: conv2, one wave per degree bucket, 8 atoms/chunk ---------------
  // Wave reads only its own atoms' rows (all k) then writes them (program order).
  // Rows disjoint across waves/chunks -> no internal barriers.
  {
    for (int pass = 0; pass < 2; ++pass) {
      const int d = wv + pass * 4;
      if (d <= 5) {
        const int beg = s_doff[d], e = s_doff[d + 1];
        if (beg < e) {
          const float2* wp2 = reinterpret_cast<const float2*>(W2 + (size_t)d * (134 * 128));
          const float2 bb = reinterpret_cast<const float2*>(b2 + (size_t)d * 128)[ln];
          for (int j = beg; j < e; j += 8) {
            const int c1 = (j + 1 < e) ? j + 1 : j, c2 = (j + 2 < e) ? j + 2 : j;
            const int c3 = (j + 3 < e) ? j + 3 : j, c4 = (j + 4 < e) ? j + 4 : j;
            const int c5 = (j + 5 < e) ? j + 5 : j, c6 = (j + 6 < e) ? j + 6 : j;
            const int c7 = (j + 7 < e) ? j + 7 : j;
            const int at0 = s_work[j],  at1 = s_work[c1], at2 = s_work[c2], at3 = s_work[c3];
            const int at4 = s_work[c4], at5 = s_work[c5], at6 = s_work[c6], at7 = s_work[c7];
            float a0x = bb.x, a0y = bb.y, a1x = bb.x, a1y = bb.y;
            float a2x = bb.x, a2y = bb.y, a3x = bb.x, a3y = bb.y;
            float a4x = bb.x, a4y = bb.y, a5x = bb.x, a5y = bb.y;
            float a6x = bb.x, a6y = bb.y, a7x = bb.x, a7y = bb.y;
            float f0, f1, f2, f3, f4, f5, f6, f7;
#pragma unroll 2
            for (int k = 0; k < 128; ++k) {
              const float2 w = wp2[k * 64 + ln];
              f0 = s_x[at0 * 128 + k]; f1 = s_x[at1 * 128 + k];
              f2 = s_x[at2 * 128 + k]; f3 = s_x[at3 * 128 + k];
              f4 = s_x[at4 * 128 + k]; f5 = s_x[at5 * 128 + k];
              f6 = s_x[at6 * 128 + k]; f7 = s_x[at7 * 128 + k];
              ACC16_FMA(w)
            }
#pragma unroll
            for (int kk = 0; kk < 6; ++kk) {
              const float2 w = wp2[(128 + kk) * 64 + ln];
              f0 = s_bsum[at0 * 8 + kk]; f1 = s_bsum[at1 * 8 + kk];
              f2 = s_bsum[at2 * 8 + kk]; f3 = s_bsum[at3 * 8 + kk];
              f4 = s_bsum[at4 * 8 + kk]; f5 = s_bsum[at5 * 8 + kk];
              f6 = s_bsum[at6 * 8 + kk]; f7 = s_bsum[at7 * 8 + kk];
              ACC16_FMA(w)
            }
            *reinterpret_cast<float2*>(&s_x[at0 * 128 + 2 * ln]) =
                make_float2(fmaxf(a0x, 0.f), fmaxf(a0y, 0.f));
            if (j + 1 < e) *reinterpret_cast<float2*>(&s_x[at1 * 128 + 2 * ln]) =
                make_float2(fmaxf(a1x, 0.f), fmaxf(a1y, 0.f));
            if (j + 2 < e) *reinterpret_cast<float2*>(&s_x[at2 * 128 + 2 * ln]) =
                make_float2(fmaxf(a2x, 0.f), fmaxf(a2y, 0.f));
            if (j + 3 < e) *reinterpret_cast<float2*>(&s_x[at3 * 128 + 2 * ln]) =
                make_float2(fmaxf(a3x, 0.f), fmaxf(a3y, 0.f));
            if (j + 4 < e) *reinterpret_cast<float2*>(&s_x[at4 * 128 + 2 * ln]) =
                make_float2(fmaxf(a4x, 0.f), fmaxf(a4y, 0.f));
            if (j + 5 < e) *reinterpret_cast<float2*>(&s_x[at5 * 128 + 2 * ln]) =
                make_float2(fmaxf(a5x, 0.f), fmaxf(a5y, 0.f));
            if (j + 6 < e) *reinterpret_cast<float2*>(&s_x[at6 * 128 + 2 * ln]) =
                make_float2(fmaxf(a6x, 0.f), fmaxf(a6y, 0.f));
            if (j + 7 < e) *reinterpret_cast<float2*>(&s_x[at7 * 128 + 2 * ln]) =
                make_float2(fmaxf(a7x, 0.f), fmaxf(a7y, 0.f));
          }
        }
      }
    }
  }
  __syncthreads();

  // ---------------- P4: pool2 in place, work members only, 0-init ----------------------
  {
    float4 v0 = nbr_wmax(sx4, s_edges, s_deg, (tid + 0 * 256) >> 5, tid & 31);
    float4 v1 = nbr_wmax(sx4, s_edges, s_deg, (tid + 1 * 256) >> 5, tid & 31);
    float4 v2 = nbr_wmax(sx4, s_edges, s_deg, (tid + 2 * 256) >> 5, tid & 31);
    float4 v3 = nbr_wmax(sx4, s_edges, s_deg, (tid + 3 * 256) >> 5, tid & 31);
    float4 v4 = nbr_wmax(sx4, s_edges, s_deg, (tid + 4 * 256) >> 5, tid & 31);
    float4 v5 = nbr_wmax(sx4, s_edges, s_deg, (tid + 5 * 256) >> 5, tid & 31);
    float4 v6 = nbr_wmax(sx4, s_edges, s_deg, (tid + 6 * 256) >> 5, tid & 31);
    float4 v7 = nbr_wmax(sx4, s_edges, s_deg, (tid + 7 * 256) >> 5, tid & 31);
    __syncthreads();
    sx4[tid + 0 * 256] = v0; sx4[tid + 1 * 256] = v1;
    sx4[tid + 2 * 256] = v2; sx4[tid + 3 * 256] = v3;
    sx4[tid + 4 * 256] = v4; sx4[tid + 5 * 256] = v5;
    sx4[tid + 6 * 256] = v6; sx4[tid + 7 * 256] = v7;
  }
  __syncthreads();

  // ---------------- P5: logits GEMM, wave-per-8-perm-slots, 2 rounds, float2 cols ------
  // Round r: wave wv owns slots r*32 + wv*8 .. +7 (4 waves x 8 x 2 = 64 rows exactly).
  // Dense 128-k loop only when sl < na (slots >= na have exactly-zero x2p rows -> dense
  // adds 0; waves fully past na skip). bsum tail + bias + write run for ALL slots
  // (covers zero rows). Each row touched by exactly one (wave, round); round-1 dense
  // reads rows of slots >=32, round-0 wrote rows of slots <32 -> disjoint -> NO barriers.
  {
    const int na = s_na;
    const float2* Wof2 = reinterpret_cast<const float2*>(Wo);
    const float2 bo2 = reinterpret_cast<const float2*>(bo)[ln];
    for (int r = 0; r < 2; ++r) {
      const int sl = r * 32 + wv * 8;
      const int at0 = s_perm[sl + 0], at1 = s_perm[sl + 1];
      const int at2 = s_perm[sl + 2], at3 = s_perm[sl + 3];
      const int at4 = s_perm[sl + 4], at5 = s_perm[sl + 5];
      const int at6 = s_perm[sl + 6], at7 = s_perm[sl + 7];
      float a0x = 0.f, a0y = 0.f, a1x = 0.f, a1y = 0.f;
      float a2x = 0.f, a2y = 0.f, a3x = 0.f, a3y = 0.f;
      float a4x = 0.f, a4y = 0.f, a5x = 0.f, a5y = 0.f;
      float a6x = 0.f, a6y = 0.f, a7x = 0.f, a7y = 0.f;
      float f0, f1, f2, f3, f4, f5, f6, f7;
      if (sl < na) {
#pragma unroll 2
        for (int k = 0; k < 128; ++k) {
          const float2 w = Wof2[k * 64 + ln];
          f0 = s_x[at0 * 128 + k]; f1 = s_x[at1 * 128 + k];
          f2 = s_x[at2 * 128 + k]; f3 = s_x[at3 * 128 + k];
          f4 = s_x[at4 * 128 + k]; f5 = s_x[at5 * 128 + k];
          f6 = s_x[at6 * 128 + k]; f7 = s_x[at7 * 128 + k];
          ACC16_FMA(w)
        }
      }
#pragma unroll
      for (int kk = 0; kk < 6; ++kk) {
        const float2 w = Wof2[(128 + kk) * 64 + ln];
        f0 = s_bsum[at0 * 8 + kk]; f1 = s_bsum[at1 * 8 + kk];
        f2 = s_bsum[at2 * 8 + kk]; f3 = s_bsum[at3 * 8 + kk];
        f4 = s_bsum[at4 * 8 + kk]; f5 = s_bsum[at5 * 8 + kk];
        f6 = s_bsum[at6 * 8 + kk]; f7 = s_bsum[at7 * 8 + kk];
        ACC16_FMA(w)
      }
      *reinterpret_cast<float2*>(&s_x[at0 * 128 + 2 * ln]) = make_float2(a0x + bo2.x, a0y + bo2.y);
      *reinterpret_cast<float2*>(&s_x[at1 * 128 + 2 * ln]) = make_float2(a1x + bo2.x, a1y + bo2.y);
      *reinterpret_cast<float2*>(&s_x[at2 * 128 + 2 * ln]) = make_float2(a2x + bo2.x, a2y + bo2.y);
      *reinterpret_cast<float2*>(&s_x[at3 * 128 + 2 * ln]) = make_float2(a3x + bo2.x, a3y + bo2.y);
      *reinterpret_cast<float2*>(&s_x[at4 * 128 + 2 * ln]) = make_float2(a4x + bo2.x, a4y + bo2.y);
      *reinterpret_cast<float2*>(&s_x[at5 * 128 + 2 * ln]) = make_float2(a5x + bo2.x, a5y + bo2.y);
      *reinterpret_cast<float2*>(&s_x[at6 * 128 + 2 * ln]) = make_float2(a6x + bo2.x, a6y + bo2.y);
      *reinterpret_cast<float2*>(&s_x[at7 * 128 + 2 * ln]) = make_float2(a7x + bo2.x, a7y + bo2.y);
    }
  }
  __syncthreads();

  // ---------------- P6: per-atom softmax over 128, 4 lanes/atom, in registers ----------
  {
    const int a = tid >> 2, q = tid & 3;
    float* base = &s_x[a * 128 + q * 32];
    const float4 v0 = *reinterpret_cast<const float4*>(base + ((0 + tid) & 7) * 4);
    const float4 v1 = *reinterpret_cast<const float4*>(base + ((1 + tid) & 7) * 4);
    const float4 v2 = *reinterpret_cast<const float4*>(base + ((2 + tid) & 7) * 4);
    const float4 v3 = *reinterpret_cast<const float4*>(base + ((3 + tid) & 7) * 4);
    const float4 v4 = *reinterpret_cast<const float4*>(base + ((4 + tid) & 7) * 4);
    const float4 v5 = *reinterpret_cast<const float4*>(base + ((5 + tid) & 7) * 4);
    const float4 v6 = *reinterpret_cast<const float4*>(base + ((6 + tid) & 7) * 4);
    const float4 v7 = *reinterpret_cast<const float4*>(base + ((7 + tid) & 7) * 4);
    float mx = fmaxf(fmaxf(fmaxf(v0.x, v0.y), fmaxf(v0.z, v0.w)),
                     fmaxf(fmaxf(v1.x, v1.y), fmaxf(v1.z, v1.w)));
    mx = fmaxf(mx, fmaxf(fmaxf(fmaxf(v2.x, v2.y), fmaxf(v2.z, v2.w)),
                         fmaxf(fmaxf(v3.x, v3.y), fmaxf(v3.z, v3.w))));
    mx = fmaxf(mx, fmaxf(fmaxf(fmaxf(v4.x, v4.y), fmaxf(v4.z, v4.w)),
                         fmaxf(fmaxf(v5.x, v5.y), fmaxf(v5.z, v5.w))));
    mx = fmaxf(mx, fmaxf(fmaxf(fmaxf(v6.x, v6.y), fmaxf(v6.z, v6.w)),
                         fmaxf(fmaxf(v7.x, v7.y), fmaxf(v7.z, v7.w))));
    mx = fmaxf(mx, __shfl_xor(mx, 1));
    mx = fmaxf(mx, __shfl_xor(mx, 2));
    float sm = 0.f;
    float4 e0, e1, e2, e3, e4, e5, e6, e7;
    e0.x = __expf(v0.x - mx); e0.y = __expf(v0.y - mx); e0.z = __expf(v0.z - mx); e0.w = __expf(v0.w - mx);
    e1.x = __expf(v1.x - mx); e1.y = __expf(v1.y - mx); e1.z = __expf(v1.z - mx); e1.w = __expf(v1.w - mx);
    e2.x = __expf(v2.x - mx); e2.y = __expf(v2.y - mx); e2.z = __expf(v2.z - mx); e2.w = __expf(v2.w - mx);
    e3.x = __expf(v3.x - mx); e3.y = __expf(v3.y - mx); e3.z = __expf(v3.z - mx); e3.w = __expf(v3.w - mx);
    e4.x = __expf(v4.x - mx); e4.y = __expf(v4.y - mx); e4.z = __expf(v4.z - mx); e4.w = __expf(v4.w - mx);
    e5.x = __expf(v5.x - mx); e5.y = __expf(v5.y - mx); e5.z = __expf(v5.z - mx); e5.w = __expf(v5.w - mx);
    e6.x = __expf(v6.x - mx); e6.y = __expf(v6.y - mx); e6.z = __expf(v6.z - mx); e6.w = __expf(v6.w - mx);
    e7.x = __expf(v7.x - mx); e7.y = __expf(v7.y - mx); e7.z = __expf(v7.z - mx); e7.w = __expf(v7.w - mx);
    sm += e0.x + e0.y + e0.z + e0.w; sm += e1.x + e1.y + e1.z + e1.w;
    sm += e2.x + e2.y + e2.z + e2.w; sm += e3.x + e3.y + e3.z + e3.w;
    sm += e4.x + e4.y + e4.z + e4.w; sm += e5.x + e5.y + e5.z + e5.w;
    sm += e6.x + e6.y + e6.z + e6.w; sm += e7.x + e7.y + e7.z + e7.w;
    *reinterpret_cast<float4*>(base + ((0 + tid) & 7) * 4) = e0;
    *reinterpret_cast<float4*>(base + ((1 + tid) & 7) * 4) = e1;
    *reinterpret_cast<float4*>(base + ((2 + tid) & 7) * 4) = e2;
    *reinterpret_cast<float4*>(base + ((3 + tid) & 7) * 4) = e3;
    *reinterpret_cast<float4*>(base + ((4 + tid) & 7) * 4) = e4;
    *reinterpret_cast<float4*>(base + ((5 + tid) & 7) * 4) = e5;
    *reinterpret_cast<float4*>(base + ((6 + tid) & 7) * 4) = e6;
    *reinterpret_cast<float4*>(base + ((7 + tid) & 7) * 4) = e7;
    sm += __shfl_xor(sm, 1);
    sm += __shfl_xor(sm, 2);
    if (q == 0) s_rsum[a] = (s_deg[a] != 0) ? (1.f / sm) : 0.f;
  }
  __syncthreads();

  // ---------------- P7: fingerprint (s_fp aliases dead s_sa) ---------------------------
  {
    const int c = tid & 127, half = tid >> 7;
    float s = 0.f;
    for (int a2 = half * 32; a2 < half * 32 + 32; ++a2)
      s = fmaf(s_x[a2 * 128 + c], s_rsum[a2], s);
    s_fp[half * 128 + c] = s;
  }
  __syncthreads();
  if (tid < 128) s_fp[tid] += s_fp[128 + tid];
  __syncthreads();

  // ---------------- P8: MLP head -------------------------------------------------------
  if (tid < 64) {
    float acc = bm1[tid];
    for (int k = 0; k < 128; ++k) acc = fmaf(s_fp[k], Wm1[k * 64 + tid], acc);
    s_h1[tid] = fmaxf(acc, 0.f);
  }
  __syncthreads();
  if (tid < 32) {
    float acc = bm2[tid];
    for (int k = 0; k < 64; ++k) acc = fmaf(s_h1[k], Wm2[k * 32 + tid], acc);
    s_h2[tid] = fmaxf(acc, 0.f);
  }
  __syncthreads();
  if (tid < 64) {
    float p = (tid < 32) ? s_h2[tid] * Wm3[tid] : 0.f;
#pragma unroll
    for (int off = 32; off > 0; off >>= 1) p += __shfl_xor(p, off);
    if (tid == 0) out[b] = p + bm3[0];
  }
}

extern "C" void kernel_launch(void* const* d_in, const int* in_sizes, int n_in,
                              void* d_out, int out_size, void* d_ws, size_t ws_size,
                              hipStream_t stream) {
  const float* atoms = (const float*)d_in[0];
  const float* bonds = (const float*)d_in[1];
  const int*   edges = (const int*)d_in[2];
  const float* W1  = (const float*)d_in[3];
  const float* b1  = (const float*)d_in[4];
  const float* W2  = (const float*)d_in[5];
  const float* b2  = (const float*)d_in[6];
  const float* Wo  = (const float*)d_in[7];
  const float* bo  = (const float*)d_in[8];
  const float* Wm1 = (const float*)d_in[9];
  const float* bm1 = (const float*)d_in[10];
  const float* Wm2 = (const float*)d_in[11];
  const float* bm2 = (const float*)d_in[12];
  const float* Wm3 = (const float*)d_in[13];
  const float* bm3 = (const float*)d_in[14];
  float* out = (float*)d_out;

  const int B = out_size;  // 4096 molecules
  qsar_fused<<<dim3(B), dim3(256), 0, stream>>>(
      atoms, bonds, edges, W1, b1, W2, b2, Wo, bo,
      Wm1, bm1, Wm2, bm2, Wm3, bm3, out);
}